// Round 1
// baseline (1378.398 us; speedup 1.0000x reference)
//
#include <hip/hip_runtime.h>

// Problem constants (fixed by the reference):
//   D: (N=16384, M=16384) fp32, x: (B=2, C_IN=4, M) fp32,
//   theta: (C_OUT=8, C_IN=4) fp32, bias: (1, 8, 1) fp32.
//   y[b,o,n] = sum_c theta[o,c] * (sum_m D[n,m] * x[b,c,m]) + bias[o]
// Memory-bound: D = 1 GiB streamed once -> ~172 us floor at 6.3 TB/s.
constexpr int kN    = 16384;
constexpr int kM    = 16384;
constexpr int kCin  = 4;
constexpr int kCout = 8;
constexpr int kBC   = 8;   // B * C_IN = flattened x rows
constexpr int ROWS_PER_WAVE  = 4;   // register row-blocking: x reads amortized 4x
constexpr int WAVES_PER_BLOCK = 4;
constexpr int ROWS_PER_BLOCK = ROWS_PER_WAVE * WAVES_PER_BLOCK; // 16

__global__ __launch_bounds__(256, 4)
void coboundary_kernel(const float* __restrict__ D,
                       const float* __restrict__ x,
                       const float* __restrict__ theta,
                       const float* __restrict__ bias,
                       float* __restrict__ out)
{
    const int lane = threadIdx.x & 63;
    const int wave = threadIdx.x >> 6;
    const int row0 = blockIdx.x * ROWS_PER_BLOCK + wave * ROWS_PER_WAVE;

    const float* dptr[ROWS_PER_WAVE];
#pragma unroll
    for (int r = 0; r < ROWS_PER_WAVE; ++r)
        dptr[r] = D + (size_t)(row0 + r) * kM;

    float acc[ROWS_PER_WAVE][kBC];
#pragma unroll
    for (int r = 0; r < ROWS_PER_WAVE; ++r)
#pragma unroll
        for (int j = 0; j < kBC; ++j)
            acc[r][j] = 0.0f;

    // Main loop: wave covers 64 lanes * float4 = 256 floats of m per iter,
    // 64 iters. 4 coalesced D float4 loads (HBM stream) + 8 x float4 loads
    // (L1/L2-resident, x is 512 KB total) + 128 FMAs per lane-iter.
    for (int m = lane * 4; m < kM; m += 64 * 4) {
        float4 xv[kBC];
#pragma unroll
        for (int j = 0; j < kBC; ++j)
            xv[j] = *(const float4*)(x + (size_t)j * kM + m);
#pragma unroll
        for (int r = 0; r < ROWS_PER_WAVE; ++r) {
            float4 dv = *(const float4*)(dptr[r] + m);
#pragma unroll
            for (int j = 0; j < kBC; ++j)
                acc[r][j] += dv.x * xv[j].x + dv.y * xv[j].y
                           + dv.z * xv[j].z + dv.w * xv[j].w;
        }
    }

    // Butterfly reduction over the 64 lanes: every lane ends with the full
    // per-row sums X[row0+r][bc]. 32 values * 6 steps = 192 shuffles,
    // amortized over 8192 main-loop FMAs (~5%).
#pragma unroll
    for (int r = 0; r < ROWS_PER_WAVE; ++r)
#pragma unroll
        for (int j = 0; j < kBC; ++j) {
            float v = acc[r][j];
#pragma unroll
            for (int off = 32; off > 0; off >>= 1)
                v += __shfl_xor(v, off, 64);
            acc[r][j] = v;
        }

    // Fused epilogue: 64 lanes = 16 (b,o) outputs x 4 rows.
    // lane = bo*4 + r so 4 consecutive lanes write 4 consecutive n (16B
    // coalesced segments per output plane).
    const int r  = lane & 3;
    const int bo = lane >> 2;     // b*8 + o
    const int b  = bo >> 3;
    const int o  = bo & 7;
    float y = bias[o];
#pragma unroll
    for (int c = 0; c < kCin; ++c)
        y += theta[o * kCin + c] * acc[r][b * kCin + c];
    out[(size_t)bo * kN + row0 + r] = y;
}

extern "C" void kernel_launch(void* const* d_in, const int* in_sizes, int n_in,
                              void* d_out, int out_size, void* d_ws, size_t ws_size,
                              hipStream_t stream) {
    const float* D     = (const float*)d_in[0];
    const float* x     = (const float*)d_in[1];
    const float* theta = (const float*)d_in[2];
    const float* bias  = (const float*)d_in[3];
    float* out = (float*)d_out;

    dim3 grid(kN / ROWS_PER_BLOCK);  // 1024 blocks -> 4 blocks/CU, 16 waves/CU
    dim3 block(WAVES_PER_BLOCK * 64);
    coboundary_kernel<<<grid, block, 0, stream>>>(D, x, theta, bias, out);
}